// Round 9
// baseline (1079.670 us; speedup 1.0000x reference)
//
#include <hip/hip_runtime.h>

// ---------------- problem constants ----------------
constexpr int CB   = 8;      // batch
constexpr int CN   = 1369;   // tokens (37*37)
constexpr int CDIN = 768;
constexpr int CS   = 7;      // slots
constexpr int CD   = 256;
constexpr int CITERS = 3;
constexpr int CRES = 37;
constexpr float CSIGMA = 5.0f;
constexpr int CBS = CB * CS;        // 56
constexpr int CBN = CB * CN;        // 10952 rows for initial mlp
constexpr float LNEPS = 1e-5f;
constexpr float ATTN_EPS = 1e-8f;

typedef unsigned short u16;
typedef short bs8 __attribute__((ext_vector_type(8)));   // 8 bf16 (bit pattern in shorts)
typedef float f4 __attribute__((ext_vector_type(4)));

// ---------------- helpers ----------------
__device__ __forceinline__ float ag_x(int n) { return -1.f + (float)(n % CRES) * (2.f / 36.f); }
__device__ __forceinline__ float ag_y(int n) { return -1.f + (float)(n / CRES) * (2.f / 36.f); }

__device__ __forceinline__ u16 bf_rne(float f) {
    unsigned u = __float_as_uint(f);
    return (u16)((u + 0x7FFFu + ((u >> 16) & 1u)) >> 16);
}
__device__ __forceinline__ float bf_to_f(u16 h) { return __uint_as_float(((unsigned)h) << 16); }

__device__ __forceinline__ void split2b(float v, u16& h, u16& m) {
    h = bf_rne(v);
    m = bf_rne(v - bf_to_f(h));
}

// 256-thread block sum
__device__ __forceinline__ float block_reduce_sum(float v, float* sbuf) {
    #pragma unroll
    for (int off = 32; off > 0; off >>= 1) v += __shfl_down(v, off, 64);
    if ((threadIdx.x & 63) == 0) sbuf[threadIdx.x >> 6] = v;
    __syncthreads();
    if (threadIdx.x == 0) sbuf[0] = sbuf[0] + sbuf[1] + sbuf[2] + sbuf[3];
    __syncthreads();
    float r = sbuf[0];
    __syncthreads();
    return r;
}

// ---------------- layernorm (fp32 out) ----------------
__global__ __launch_bounds__(256) void ln_kernel(const float* __restrict__ in,
        float* __restrict__ out, const float* __restrict__ g,
        const float* __restrict__ b, int d) {
    __shared__ float sbuf[8];
    int row = blockIdx.x;
    const float* x = in + (size_t)row * d;
    float* y = out + (size_t)row * d;
    float s = 0.f;
    for (int i = threadIdx.x; i < d; i += 256) s += x[i];
    float mean = block_reduce_sum(s, sbuf) / d;
    float v = 0.f;
    for (int i = threadIdx.x; i < d; i += 256) { float t = x[i] - mean; v += t * t; }
    float var = block_reduce_sum(v, sbuf) / d;
    float rstd = rsqrtf(var + LNEPS);
    for (int i = threadIdx.x; i < d; i += 256) y[i] = (x[i] - mean) * rstd * g[i] + b[i];
}

// ---------------- transpose fp32 W[K][N] -> 2 bf16 planes Wt[N][K] ----------------
__global__ __launch_bounds__(256) void transpose_split2_kernel(const float* __restrict__ W,
        u16* __restrict__ Th, u16* __restrict__ Tm, int K, int N) {
    __shared__ float tile[32][33];
    int nb = blockIdx.x * 32, kb = blockIdx.y * 32;
    int tx = threadIdx.x & 31, ty = threadIdx.x >> 5;   // ty 0..7
    #pragma unroll
    for (int i = 0; i < 32; i += 8)
        tile[ty + i][tx] = W[(size_t)(kb + ty + i) * N + nb + tx];
    __syncthreads();
    #pragma unroll
    for (int i = 0; i < 32; i += 8) {
        float v = tile[tx][ty + i];
        u16 h, m; split2b(v, h, m);
        size_t idx = (size_t)(nb + ty + i) * K + kb + tx;
        Th[idx] = h; Tm[idx] = m;
    }
}

// ---------------- fp32 transpose W[K][N] -> T[N][K] ----------------
__global__ __launch_bounds__(256) void transpose32_kernel(const float* __restrict__ W,
        float* __restrict__ T, int K, int N) {
    __shared__ float tile[32][33];
    int nb = blockIdx.x * 32, kb = blockIdx.y * 32;
    int tx = threadIdx.x & 31, ty = threadIdx.x >> 5;
    #pragma unroll
    for (int i = 0; i < 32; i += 8)
        tile[ty + i][tx] = W[(size_t)(kb + ty + i) * N + nb + tx];
    __syncthreads();
    #pragma unroll
    for (int i = 0; i < 32; i += 8)
        T[(size_t)(nb + ty + i) * K + kb + tx] = tile[tx][ty + i];
}

// ---------------- small fp32 weight-product: P[k][n] = sum_j A[k][j]*B[j][n], [256]x[256] ----------------
__global__ __launch_bounds__(256) void wprod_kernel(const float* __restrict__ A,
        const float* __restrict__ B, float* __restrict__ P) {
    __shared__ float arow[CD];
    int k = blockIdx.x, n = threadIdx.x;
    arow[n] = A[k * CD + n];
    __syncthreads();
    float acc = 0.f;
    for (int j = 0; j < CD; j++) acc += arow[j] * B[j * CD + n];
    P[k * CD + n] = acc;
}

// G2[g][n] = sum_j g_w[g][j]*f_w1[j][n];  gb1[n] = sum_j g_b[j]*f_w1[j][n] + f_b1[n]
__global__ __launch_bounds__(256) void g2_kernel(const float* __restrict__ g_w,
        const float* __restrict__ g_b, const float* __restrict__ f_w1,
        const float* __restrict__ f_b1, float* __restrict__ G2, float* __restrict__ gb1) {
    int n = threadIdx.x;
    float a0 = 0.f, a1 = 0.f, ab = 0.f;
    for (int j = 0; j < CD; j++) {
        float w = f_w1[j * CD + n];
        a0 += g_w[j] * w;
        a1 += g_w[CD + j] * w;
        ab += g_b[j] * w;
    }
    G2[n] = a0; G2[CD + n] = a1; gb1[n] = ab + f_b1[n];
}

// wqb[j] = sum_c Wq[j][c] * f_b2[c]
__global__ __launch_bounds__(256) void wqb_kernel(const float* __restrict__ Wq,
        const float* __restrict__ f_b2, float* __restrict__ wqb) {
    int j = threadIdx.x;
    float s = 0.f;
    for (int c = 0; c < CD; c++) s += Wq[j * CD + c] * f_b2[c];
    wqb[j] = s;
}

// ---------------- bf16x3 (split-2 planes) TN GEMM — big M (init phase) ----------------
__global__ __launch_bounds__(256)
void hgemm(const float* __restrict__ A,
           const u16* __restrict__ Bh, const u16* __restrict__ Bm,
           int M, int N, int K, const float* __restrict__ bias, int relu,
           float* __restrict__ Cf) {
    constexpr int PK = 40;
    __shared__ short smem[4 * 128 * PK];         // 40 KB
    short* Ash = smem;
    short* Asm_ = smem + 128 * PK;
    short* Bsh = smem + 2 * 128 * PK;
    short* Bsm = smem + 3 * 128 * PK;
    const int tid = threadIdx.x;
    const int m0 = blockIdx.x * 128, n0 = blockIdx.y * 128;
    const int w = tid >> 6, lane = tid & 63;
    const int wm = w & 1, wn = w >> 1;
    const int l15 = lane & 15, l4 = lane >> 4;
    const int sr = tid >> 2;
    const int sc = (tid & 3) * 8;

    const float* asrc[2];
    #pragma unroll
    for (int it = 0; it < 2; it++) {
        int grow = m0 + sr + it * 64;
        int gcl = grow < M ? grow : M - 1;
        asrc[it] = A + (size_t)gcl * K + sc;
    }

    f4 acc[4][4];
    #pragma unroll
    for (int i = 0; i < 4; i++)
        #pragma unroll
        for (int j = 0; j < 4; j++) acc[i][j] = (f4){0.f, 0.f, 0.f, 0.f};

    for (int k0 = 0; k0 < K; k0 += 32) {
        #pragma unroll
        for (int it = 0; it < 2; it++) {
            int r = sr + it * 64;
            float v8[8];
            const float* p = asrc[it] + k0;
            *(float4*)&v8[0] = *(const float4*)(p);
            *(float4*)&v8[4] = *(const float4*)(p + 4);
            bs8 hv, mv;
            #pragma unroll
            for (int j = 0; j < 8; j++) {
                u16 h, m; split2b(v8[j], h, m);
                hv[j] = (short)h; mv[j] = (short)m;
            }
            *(bs8*)(Ash  + r * PK + sc) = hv;
            *(bs8*)(Asm_ + r * PK + sc) = mv;
            int nr = n0 + r;
            size_t bofs = (size_t)nr * K + k0 + sc;
            *(bs8*)(Bsh + r * PK + sc) = *(const bs8*)(Bh + bofs);
            *(bs8*)(Bsm + r * PK + sc) = *(const bs8*)(Bm + bofs);
        }
        __syncthreads();
        bs8 ah[4], am[4], bh[4], bm[4];
        #pragma unroll
        for (int f = 0; f < 4; f++) {
            int ra = (wm * 64 + f * 16 + l15) * PK + l4 * 8;
            ah[f] = *(const bs8*)(Ash  + ra);
            am[f] = *(const bs8*)(Asm_ + ra);
            int rb = (wn * 64 + f * 16 + l15) * PK + l4 * 8;
            bh[f] = *(const bs8*)(Bsh + rb);
            bm[f] = *(const bs8*)(Bsm + rb);
        }
        #pragma unroll
        for (int mf = 0; mf < 4; mf++)
            #pragma unroll
            for (int nf = 0; nf < 4; nf++) {
                acc[mf][nf] = __builtin_amdgcn_mfma_f32_16x16x32_bf16(am[mf], bh[nf], acc[mf][nf], 0, 0, 0);
                acc[mf][nf] = __builtin_amdgcn_mfma_f32_16x16x32_bf16(ah[mf], bm[nf], acc[mf][nf], 0, 0, 0);
                acc[mf][nf] = __builtin_amdgcn_mfma_f32_16x16x32_bf16(ah[mf], bh[nf], acc[mf][nf], 0, 0, 0);
            }
        __syncthreads();
    }

    #pragma unroll
    for (int mf = 0; mf < 4; mf++)
        #pragma unroll
        for (int i = 0; i < 4; i++) {
            int grow = m0 + wm * 64 + mf * 16 + l4 * 4 + i;
            if (grow < M) {
                #pragma unroll
                for (int nf = 0; nf < 4; nf++) {
                    int col = n0 + wn * 64 + nf * 16 + l15;
                    float v = acc[mf][nf][i] + (bias ? bias[col] : 0.f);
                    if (relu) v = fmaxf(v, 0.f);
                    Cf[(size_t)grow * N + col] = v;
                }
            }
        }
}

// ---------------- small-M (M<=128) GEMM, grid (1, N/128, Z); Z>1 => K-split + atomicAdd ----------------
template<int ATOMIC>
__global__ __launch_bounds__(256)
void hgemmS(const float* __restrict__ A,
            const u16* __restrict__ Bh, const u16* __restrict__ Bm,
            int M, int N, int Ktot, int KC,
            const float* __restrict__ bias, int relu, float* __restrict__ Cf) {
    constexpr int PK = 40;
    __shared__ short smem[4 * 128 * PK];
    short* Ash = smem;
    short* Asm_ = smem + 128 * PK;
    short* Bsh = smem + 2 * 128 * PK;
    short* Bsm = smem + 3 * 128 * PK;
    const int tid = threadIdx.x;
    const int n0 = blockIdx.y * 128;
    const int kbeg = blockIdx.z * KC;
    const int w = tid >> 6, lane = tid & 63;
    const int wm = w & 1, wn = w >> 1;
    const int l15 = lane & 15, l4 = lane >> 4;
    const int sr = tid >> 2;
    const int sc = (tid & 3) * 8;

    const float* asrc[2];
    #pragma unroll
    for (int it = 0; it < 2; it++) {
        int grow = sr + it * 64;
        int gcl = grow < M ? grow : M - 1;
        asrc[it] = A + (size_t)gcl * Ktot + sc;
    }

    f4 acc[4][4];
    #pragma unroll
    for (int i = 0; i < 4; i++)
        #pragma unroll
        for (int j = 0; j < 4; j++) acc[i][j] = (f4){0.f, 0.f, 0.f, 0.f};

    for (int k0 = kbeg; k0 < kbeg + KC; k0 += 32) {
        #pragma unroll
        for (int it = 0; it < 2; it++) {
            int r = sr + it * 64;
            float v8[8];
            const float* p = asrc[it] + k0;
            *(float4*)&v8[0] = *(const float4*)(p);
            *(float4*)&v8[4] = *(const float4*)(p + 4);
            bs8 hv, mv;
            #pragma unroll
            for (int j = 0; j < 8; j++) {
                u16 h, m; split2b(v8[j], h, m);
                hv[j] = (short)h; mv[j] = (short)m;
            }
            *(bs8*)(Ash  + r * PK + sc) = hv;
            *(bs8*)(Asm_ + r * PK + sc) = mv;
            int nr = n0 + r;
            size_t bofs = (size_t)nr * Ktot + k0 + sc;
            *(bs8*)(Bsh + r * PK + sc) = *(const bs8*)(Bh + bofs);
            *(bs8*)(Bsm + r * PK + sc) = *(const bs8*)(Bm + bofs);
        }
        __syncthreads();
        bs8 ah[4], am[4], bh[4], bm[4];
        #pragma unroll
        for (int f = 0; f < 4; f++) {
            int ra = (wm * 64 + f * 16 + l15) * PK + l4 * 8;
            ah[f] = *(const bs8*)(Ash  + ra);
            am[f] = *(const bs8*)(Asm_ + ra);
            int rb = (wn * 64 + f * 16 + l15) * PK + l4 * 8;
            bh[f] = *(const bs8*)(Bsh + rb);
            bm[f] = *(const bs8*)(Bsm + rb);
        }
        #pragma unroll
        for (int mf = 0; mf < 4; mf++)
            #pragma unroll
            for (int nf = 0; nf < 4; nf++) {
                acc[mf][nf] = __builtin_amdgcn_mfma_f32_16x16x32_bf16(am[mf], bh[nf], acc[mf][nf], 0, 0, 0);
                acc[mf][nf] = __builtin_amdgcn_mfma_f32_16x16x32_bf16(ah[mf], bm[nf], acc[mf][nf], 0, 0, 0);
                acc[mf][nf] = __builtin_amdgcn_mfma_f32_16x16x32_bf16(ah[mf], bh[nf], acc[mf][nf], 0, 0, 0);
            }
        __syncthreads();
    }

    #pragma unroll
    for (int mf = 0; mf < 4; mf++)
        #pragma unroll
        for (int i = 0; i < 4; i++) {
            int grow = wm * 64 + mf * 16 + l4 * 4 + i;
            if (grow < M) {
                #pragma unroll
                for (int nf = 0; nf < 4; nf++) {
                    int col = n0 + wn * 64 + nf * 16 + l15;
                    float v = acc[mf][nf][i] + (bias ? bias[col] : 0.f);
                    if (relu) v = fmaxf(v, 0.f);
                    if constexpr (ATOMIC) atomicAdd(&Cf[(size_t)grow * N + col], v);
                    else Cf[(size_t)grow * N + col] = v;
                }
            }
        }
}

// ---------------- small kernels ----------------
__global__ __launch_bounds__(256) void init_kernel(const float* __restrict__ slots_init_p,
        const float* __restrict__ S_s0, const float* __restrict__ S_p0,
        float* __restrict__ slots, float* __restrict__ S_s, float* __restrict__ S_p) {
    int bs = blockIdx.x, t = threadIdx.x;
    int s = bs % CS;
    slots[bs * CD + t] = slots_init_p[s * CD + t];
    if (t < 2) { S_s[bs * 2 + t] = S_s0[s * 2 + t]; S_p[bs * 2 + t] = S_p0[s * 2 + t]; }
}

// LN(slots) -> snb; qb0[bs] = sn . wqb
__global__ __launch_bounds__(256) void ln_slots_kernel(const float* __restrict__ slots,
        const float* __restrict__ ln_g, const float* __restrict__ ln_b,
        const float* __restrict__ wqb, float* __restrict__ snb, float* __restrict__ qb0) {
    __shared__ float sbuf[8];
    int row = blockIdx.x, t = threadIdx.x;
    float x = slots[row * CD + t];
    float mean = block_reduce_sum(x, sbuf) / CD;
    float d0 = x - mean;
    float var = block_reduce_sum(d0 * d0, sbuf) / CD;
    float sn = d0 * rsqrtf(var + LNEPS) * ln_g[t] + ln_b[t];
    snb[row * CD + t] = sn;
    float qb = block_reduce_sum(sn * wqb[t], sbuf);
    if (t == 0) qb0[row] = qb;
}

// dots[(b,s),n] = scale*( qw[bs] . relu(KXW1[b,n] + r0*G2[0] + r1*G2[1] + gb1) + qb0[bs] )
__global__ __launch_bounds__(256) void dots_kernel(const float* __restrict__ KXW1,
        const float* __restrict__ S_p, const float* __restrict__ S_s,
        const float* __restrict__ G2, const float* __restrict__ gb1,
        const float* __restrict__ qw, const float* __restrict__ qb0,
        float* __restrict__ dots) {
    int b = blockIdx.x;
    int w = threadIdx.x >> 6, l = threadIdx.x & 63;
    int k4 = l * 4;
    float4 g0 = *(const float4*)(G2 + k4);
    float4 g1 = *(const float4*)(G2 + CD + k4);
    float4 gb = *(const float4*)(gb1 + k4);
    float4 qwv[CS]; float px[CS], py[CS], ix[CS], iy[CS], q0[CS];
    #pragma unroll
    for (int s = 0; s < CS; s++) {
        int bs = b * CS + s;
        qwv[s] = *(const float4*)(qw + bs * CD + k4);
        px[s] = S_p[2 * bs]; py[s] = S_p[2 * bs + 1];
        ix[s] = 1.f / (S_s[2 * bs] * CSIGMA); iy[s] = 1.f / (S_s[2 * bs + 1] * CSIGMA);
        q0[s] = qb0[bs];
    }
    for (int i = 0; i < 8; i++) {
        int n = blockIdx.y * 32 + w * 8 + i;
        if (n >= CN) break;
        float4 kx = *(const float4*)(KXW1 + (size_t)(b * CN + n) * CD + k4);
        float ax = ag_x(n), ay = ag_y(n);
        #pragma unroll
        for (int s = 0; s < CS; s++) {
            float r0 = (ax - px[s]) * ix[s];
            float r1 = (ay - py[s]) * iy[s];
            float v0 = fmaxf(kx.x + r0 * g0.x + r1 * g1.x + gb.x, 0.f);
            float v1 = fmaxf(kx.y + r0 * g0.y + r1 * g1.y + gb.y, 0.f);
            float v2 = fmaxf(kx.z + r0 * g0.z + r1 * g1.z + gb.z, 0.f);
            float v3 = fmaxf(kx.w + r0 * g0.w + r1 * g1.w + gb.w, 0.f);
            float d = v0 * qwv[s].x + v1 * qwv[s].y + v2 * qwv[s].z + v3 * qwv[s].w;
            #pragma unroll
            for (int off = 32; off > 0; off >>= 1) d += __shfl_down(d, off, 64);
            if (l == 0) dots[(size_t)(b * CS + s) * CN + n] = 0.0625f * (d + q0[s]);
        }
    }
}

// Wacc[bs][k] += sum_n attn[bs,n] * relu(VXW1[b,n,k] + r0*G2[0][k] + r1*G2[1][k] + gb1[k])
__global__ __launch_bounds__(256) void vsum_kernel(const float* __restrict__ VXW1,
        const float* __restrict__ S_p, const float* __restrict__ S_s,
        const float* __restrict__ G2, const float* __restrict__ gb1,
        const float* __restrict__ attn, float* __restrict__ Wacc) {
    __shared__ float sred[4 * CD];
    int b = blockIdx.x;
    int w = threadIdx.x >> 6, l = threadIdx.x & 63;
    int k4 = l * 4;
    float4 g0 = *(const float4*)(G2 + k4);
    float4 g1 = *(const float4*)(G2 + CD + k4);
    float4 gb = *(const float4*)(gb1 + k4);
    float px[CS], py[CS], ix[CS], iy[CS];
    #pragma unroll
    for (int s = 0; s < CS; s++) {
        int bs = b * CS + s;
        px[s] = S_p[2 * bs]; py[s] = S_p[2 * bs + 1];
        ix[s] = 1.f / (S_s[2 * bs] * CSIGMA); iy[s] = 1.f / (S_s[2 * bs + 1] * CSIGMA);
    }
    float4 acc[CS];
    #pragma unroll
    for (int s = 0; s < CS; s++) acc[s] = make_float4(0.f, 0.f, 0.f, 0.f);
    for (int i = 0; i < 8; i++) {
        int n = blockIdx.y * 32 + w * 8 + i;
        if (n >= CN) break;
        float4 vx = *(const float4*)(VXW1 + (size_t)(b * CN + n) * CD + k4);
        float ax = ag_x(n), ay = ag_y(n);
        #pragma unroll
        for (int s = 0; s < CS; s++) {
            float r0 = (ax - px[s]) * ix[s];
            float r1 = (ay - py[s]) * iy[s];
            float a = attn[(size_t)(b * CS + s) * CN + n];
            acc[s].x += a * fmaxf(vx.x + r0 * g0.x + r1 * g1.x + gb.x, 0.f);
            acc[s].y += a * fmaxf(vx.y + r0 * g0.y + r1 * g1.y + gb.y, 0.f);
            acc[s].z += a * fmaxf(vx.z + r0 * g0.z + r1 * g1.z + gb.z, 0.f);
            acc[s].w += a * fmaxf(vx.w + r0 * g0.w + r1 * g1.w + gb.w, 0.f);
        }
    }
    for (int s = 0; s < CS; s++) {
        ((float4*)sred)[w * 64 + l] = acc[s];
        __syncthreads();
        if (threadIdx.x < CD) {
            float v = sred[threadIdx.x] + sred[CD + threadIdx.x]
                    + sred[2 * CD + threadIdx.x] + sred[3 * CD + threadIdx.x];
            atomicAdd(&Wacc[(size_t)(b * CS + s) * CD + threadIdx.x], v);
        }
        __syncthreads();
    }
}

__global__ __launch_bounds__(256) void softmax_kernel(float* __restrict__ dots) {
    int idx = blockIdx.x * 256 + threadIdx.x;
    if (idx >= CBN) return;
    int b = idx / CN, n = idx - b * CN;
    float v[CS]; float mx = -1e30f;
    #pragma unroll
    for (int s = 0; s < CS; s++) { v[s] = dots[(size_t)(b * CS + s) * CN + n]; mx = fmaxf(mx, v[s]); }
    float sum = 0.f;
    #pragma unroll
    for (int s = 0; s < CS; s++) { v[s] = __expf(v[s] - mx); sum += v[s]; }
    float inv = 1.f / sum;
    #pragma unroll
    for (int s = 0; s < CS; s++) dots[(size_t)(b * CS + s) * CN + n] = v[s] * inv + ATTN_EPS;
}

__global__ __launch_bounds__(256) void attn_moments_kernel(float* __restrict__ u,
        float* __restrict__ S_p, float* __restrict__ S_s) {
    __shared__ float sbuf[8];
    int bs = blockIdx.x;
    float* up = u + (size_t)bs * CN;
    float m0 = 0, m1x = 0, m1y = 0, m2x = 0, m2y = 0;
    for (int n = threadIdx.x; n < CN; n += 256) {
        float uu = up[n];
        float ax = ag_x(n), ay = ag_y(n);
        m0 += uu; m1x += uu * ax; m1y += uu * ay; m2x += uu * ax * ax; m2y += uu * ay * ay;
    }
    m0  = block_reduce_sum(m0, sbuf);
    m1x = block_reduce_sum(m1x, sbuf);
    m1y = block_reduce_sum(m1y, sbuf);
    m2x = block_reduce_sum(m2x, sbuf);
    m2y = block_reduce_sum(m2y, sbuf);
    float px = m1x / m0, py = m1y / m0;
    if (threadIdx.x == 0) {
        S_p[2 * bs] = px; S_p[2 * bs + 1] = py;
        S_s[2 * bs]     = sqrtf(fmaxf(m2x / m0 - px * px, 0.f));
        S_s[2 * bs + 1] = sqrtf(fmaxf(m2y / m0 - py * py, 0.f));
    }
    float inv = 1.f / m0;
    for (int n = threadIdx.x; n < CN; n += 256) up[n] = up[n] * inv;
}

// gates + LN: snew from giRaw/ghRaw, then LN -> sM
__global__ __launch_bounds__(256) void gate_ln_kernel(const float* __restrict__ giRaw,
        const float* __restrict__ ghRaw, const float* __restrict__ bih,
        const float* __restrict__ bhh, const float* __restrict__ slots,
        const float* __restrict__ mg, const float* __restrict__ mb,
        float* __restrict__ snewb, float* __restrict__ sMb) {
    __shared__ float sbuf[8];
    int row = blockIdx.x, t = threadIdx.x;
    float gi0 = giRaw[row * 3 * CD + t]          + bih[t];
    float gi1 = giRaw[row * 3 * CD + CD + t]     + bih[CD + t];
    float gi2 = giRaw[row * 3 * CD + 2 * CD + t] + bih[2 * CD + t];
    float gh0 = ghRaw[row * 3 * CD + t]          + bhh[t];
    float gh1 = ghRaw[row * 3 * CD + CD + t]     + bhh[CD + t];
    float gh2 = ghRaw[row * 3 * CD + 2 * CD + t] + bhh[2 * CD + t];
    float r = 1.f / (1.f + expf(-(gi0 + gh0)));
    float z = 1.f / (1.f + expf(-(gi1 + gh1)));
    float nn = tanhf(gi2 + r * gh2);
    float snew = (1.f - z) * nn + z * slots[row * CD + t];
    snewb[row * CD + t] = snew;
    float mean = block_reduce_sum(snew, sbuf) / CD;
    float dv = snew - mean;
    float var = block_reduce_sum(dv * dv, sbuf) / CD;
    sMb[row * CD + t] = dv * rsqrtf(var + LNEPS) * mg[t] + mb[t];
}

// slots = snewb + b2 + Macc
__global__ __launch_bounds__(256) void residual_kernel(const float* __restrict__ snewb,
        const float* __restrict__ b2, const float* __restrict__ Macc,
        float* __restrict__ slots) {
    int row = blockIdx.x, t = threadIdx.x;
    slots[row * CD + t] = snewb[row * CD + t] + b2[t] + Macc[row * CD + t];
}

// ---------------- launcher ----------------
extern "C" void kernel_launch(void* const* d_in, const int* in_sizes, int n_in,
                              void* d_out, int out_size, void* d_ws, size_t ws_size,
                              hipStream_t stream) {
    (void)in_sizes; (void)n_in; (void)out_size;
    const float* inputs       = (const float*)d_in[0];
    const float* slots_init_p = (const float*)d_in[1];
    const float* S_s0         = (const float*)d_in[2];
    const float* S_p0         = (const float*)d_in[3];
    const float* im_ln1_g = (const float*)d_in[4];
    const float* im_ln1_b = (const float*)d_in[5];
    const float* im_w1    = (const float*)d_in[6];
    const float* im_b1    = (const float*)d_in[7];
    const float* im_w2    = (const float*)d_in[8];
    const float* im_b2    = (const float*)d_in[9];
    const float* im_ln2_g = (const float*)d_in[10];
    const float* im_ln2_b = (const float*)d_in[11];
    const float* Wq  = (const float*)d_in[12];
    const float* Wk  = (const float*)d_in[13];
    const float* Wv  = (const float*)d_in[14];
    const float* g_w = (const float*)d_in[15];
    const float* g_b = (const float*)d_in[16];
    const float* f_w1 = (const float*)d_in[17];
    const float* f_b1 = (const float*)d_in[18];
    const float* f_w2 = (const float*)d_in[19];
    const float* f_b2 = (const float*)d_in[20];
    const float* ln_g = (const float*)d_in[21];
    const float* ln_b = (const float*)d_in[22];
    const float* gru_wih = (const float*)d_in[23];
    const float* gru_whh = (const float*)d_in[24];
    const float* gru_bih = (const float*)d_in[25];
    const float* gru_bhh = (const float*)d_in[26];
    const float* mlp_ln_g = (const float*)d_in[27];
    const float* mlp_ln_b = (const float*)d_in[28];
    const float* mlp_w1 = (const float*)d_in[29];
    const float* mlp_b1 = (const float*)d_in[30];
    const float* mlp_w2 = (const float*)d_in[31];
    const float* mlp_b2 = (const float*)d_in[32];
    const float* fin_w = (const float*)d_in[33];
    const float* fin_b = (const float*)d_in[34];

    char* base = (char*)d_ws;
    size_t off = 0;
    auto take = [&](size_t bytes) { void* p = base + off; off += (bytes + 255) & ~(size_t)255; return p; };

    float* R1 = (float*)take((size_t)CBN * CDIN * 4);  // xln; later xD | xDn
    float* R2 = (float*)take((size_t)CBN * CDIN * 4);  // X1; later KXW1 | VXW1
    u16* w1th = (u16*)take((size_t)CDIN * CDIN * 2);
    u16* w1tm = (u16*)take((size_t)CDIN * CDIN * 2);
    u16* w2th = (u16*)take((size_t)CDIN * CD * 2);
    u16* w2tm = (u16*)take((size_t)CDIN * CD * 2);
    u16* fw2h = (u16*)take((size_t)CD * CD * 2);       // f_w2 transposed planes (for upd GEMM)
    u16* fw2m = (u16*)take((size_t)CD * CD * 2);
    float* Pk   = (float*)take((size_t)CD * CD * 4);
    float* Pv   = (float*)take((size_t)CD * CD * 4);
    u16* pkth = (u16*)take((size_t)CD * CD * 2);
    u16* pktm = (u16*)take((size_t)CD * CD * 2);
    u16* pvth = (u16*)take((size_t)CD * CD * 2);
    u16* pvtm = (u16*)take((size_t)CD * CD * 2);
    float* G2b  = (float*)take((size_t)2 * CD * 4);
    float* gb1b = (float*)take((size_t)CD * 4);
    float* fw2T = (float*)take((size_t)CD * CD * 4);   // f_w2^T fp32
    float* Pq   = (float*)take((size_t)CD * CD * 4);   // Wq @ f_w2^T
    u16* pqth = (u16*)take((size_t)CD * CD * 2);
    u16* pqtm = (u16*)take((size_t)CD * CD * 2);
    u16* wihTh = (u16*)take((size_t)CD * 3 * CD * 2);  // [768][256]
    u16* wihTm = (u16*)take((size_t)CD * 3 * CD * 2);
    u16* whhTh = (u16*)take((size_t)CD * 3 * CD * 2);
    u16* whhTm = (u16*)take((size_t)CD * 3 * CD * 2);
    u16* w1Th = (u16*)take((size_t)CD * 4 * CD * 2);   // [1024][256]
    u16* w1Tm = (u16*)take((size_t)CD * 4 * CD * 2);
    u16* w2Th = (u16*)take((size_t)CD * 4 * CD * 2);   // [256][1024]
    u16* w2Tm = (u16*)take((size_t)CD * 4 * CD * 2);
    u16* finTh = (u16*)take((size_t)CD * CD * 2);
    u16* finTm = (u16*)take((size_t)CD * CD * 2);
    float* wqbb = (float*)take((size_t)CD * 4);
    float* snb   = (float*)take((size_t)CBS * CD * 4);
    float* qwb   = (float*)take((size_t)CBS * CD * 4);
    float* qb0b  = (float*)take((size_t)CBS * 4);
    float* Wacc  = (float*)take((size_t)CBS * CD * 4);
    float* updb  = (float*)take((size_t)CBS * CD * 4);
    float* giRaw = (float*)take((size_t)CBS * 3 * CD * 4);
    float* ghRaw = (float*)take((size_t)CBS * 3 * CD * 4);
    float* snewb = (float*)take((size_t)CBS * CD * 4);
    float* sMb   = (float*)take((size_t)CBS * CD * 4);
    float* h1b   = (float*)take((size_t)CBS * 4 * CD * 4);
    float* Macc  = (float*)take((size_t)CBS * CD * 4);
    float* S_pA  = (float*)take((size_t)CBS * 2 * 4);
    float* S_sA  = (float*)take((size_t)CBS * 2 * 4);
    float* S_pB  = (float*)take((size_t)CBS * 2 * 4);
    float* S_sB  = (float*)take((size_t)CBS * 2 * 4);
    float* slots = (float*)take((size_t)CBS * CD * 4);
    if (ws_size < off) return;

    float* xln  = R1;
    float* xD   = R1;
    float* xDn  = R1 + (size_t)CBN * CD;
    float* X1   = R2;
    float* KXW1 = R2;
    float* VXW1 = R2 + (size_t)CBN * CD;

    float* out0 = (float*)d_out;            // [CBS,CD]
    float* attnb = out0 + CBS * CD;         // [CBS,CN] — dots/attn buffer

    dim3 blk(256);
    const int gM_bn = (CBN + 127) / 128;    // 86
    dim3 gridBN(CB, (CN + 31) / 32);        // 8 x 43

    // ---- weight prep ----
    transpose_split2_kernel<<<dim3(CDIN/32, CDIN/32), blk, 0, stream>>>(im_w1, w1th, w1tm, CDIN, CDIN);
    transpose_split2_kernel<<<dim3(CD/32,   CDIN/32), blk, 0, stream>>>(im_w2, w2th, w2tm, CDIN, CD);
    transpose_split2_kernel<<<dim3(CD/32,   CD/32),   blk, 0, stream>>>(f_w2, fw2h, fw2m, CD, CD);
    wprod_kernel<<<CD, blk, 0, stream>>>(Wk, f_w1, Pk);
    wprod_kernel<<<CD, blk, 0, stream>>>(Wv, f_w1, Pv);
    transpose_split2_kernel<<<dim3(CD/32, CD/32), blk, 0, stream>>>(Pk, pkth, pktm, CD, CD);
    transpose_split2_kernel<<<dim3(CD/32, CD/32), blk, 0, stream>>>(Pv, pvth, pvtm, CD, CD);
    g2_kernel<<<1, blk, 0, stream>>>(g_w, g_b, f_w1, f_b1, G2b, gb1b);
    transpose32_kernel<<<dim3(CD/32, CD/32), blk, 0, stream>>>(f_w2, fw2T, CD, CD);
    wprod_kernel<<<CD, blk, 0, stream>>>(Wq, fw2T, Pq);
    transpose_split2_kernel<<<dim3(CD/32, CD/32), blk, 0, stream>>>(Pq, pqth, pqtm, CD, CD);
    transpose_split2_kernel<<<dim3(3*CD/32, CD/32), blk, 0, stream>>>(gru_wih, wihTh, wihTm, CD, 3*CD);
    transpose_split2_kernel<<<dim3(3*CD/32, CD/32), blk, 0, stream>>>(gru_whh, whhTh, whhTm, CD, 3*CD);
    transpose_split2_kernel<<<dim3(4*CD/32, CD/32), blk, 0, stream>>>(mlp_w1, w1Th, w1Tm, CD, 4*CD);
    transpose_split2_kernel<<<dim3(CD/32, 4*CD/32), blk, 0, stream>>>(mlp_w2, w2Th, w2Tm, 4*CD, CD);
    transpose_split2_kernel<<<dim3(CD/32, CD/32), blk, 0, stream>>>(fin_w, finTh, finTm, CD, CD);
    wqb_kernel<<<1, blk, 0, stream>>>(Wq, f_b2, wqbb);

    // ---- initial mlp ----
    ln_kernel<<<CBN, blk, 0, stream>>>(inputs, xln, im_ln1_g, im_ln1_b, CDIN);
    hgemm<<<dim3(gM_bn, CDIN/128), blk, 0, stream>>>(xln, w1th, w1tm, CBN, CDIN, CDIN, im_b1, 1, X1);
    hgemm<<<dim3(gM_bn, CD/128), blk, 0, stream>>>(X1, w2th, w2tm, CBN, CD, CDIN, im_b2, 0, xD);
    ln_kernel<<<CBN, blk, 0, stream>>>(xD, xDn, im_ln2_g, im_ln2_b, CD);
    hgemm<<<dim3(gM_bn, CD/128), blk, 0, stream>>>(xDn, pkth, pktm, CBN, CD, CD, nullptr, 0, KXW1);
    hgemm<<<dim3(gM_bn, CD/128), blk, 0, stream>>>(xDn, pvth, pvtm, CBN, CD, CD, nullptr, 0, VXW1);
    init_kernel<<<CBS, blk, 0, stream>>>(slots_init_p, S_s0, S_p0, slots, S_sA, S_pA);

    for (int t = 0; t <= CITERS; t++) {
        float* Sp_cur = (t & 1) ? S_pB : S_pA;
        float* Ss_cur = (t & 1) ? S_sB : S_sA;
        float* Sp_nxt = (t & 1) ? S_pA : S_pB;
        float* Ss_nxt = (t & 1) ? S_sA : S_sB;
        ln_slots_kernel<<<CBS, blk, 0, stream>>>(slots, ln_g, ln_b, wqbb, snb, qb0b);
        // qw = sn @ Pq   (Pq = Wq @ f_w2^T)
        hgemmS<0><<<dim3(1, CD/128), blk, 0, stream>>>(snb, pqth, pqtm, CBS, CD, CD, CD,
            nullptr, 0, qwb);
        dots_kernel<<<gridBN, blk, 0, stream>>>(KXW1, Sp_cur, Ss_cur, G2b, gb1b, qwb, qb0b, attnb);
        softmax_kernel<<<(CBN + 255) / 256, blk, 0, stream>>>(attnb);
        attn_moments_kernel<<<CBS, blk, 0, stream>>>(attnb, Sp_nxt, Ss_nxt);
        if (t < CITERS) {
            hipMemsetAsync(Wacc, 0, (size_t)CBS * CD * sizeof(float), stream);
            vsum_kernel<<<gridBN, blk, 0, stream>>>(VXW1, Sp_cur, Ss_cur, G2b, gb1b, attnb, Wacc);
            // upd = Wacc @ f_w2 + f_b2
            hgemmS<0><<<dim3(1, CD/128), blk, 0, stream>>>(Wacc, fw2h, fw2m, CBS, CD, CD, CD,
                f_b2, 0, updb);
            // giRaw = upd @ wih ; ghRaw = slots @ whh
            hgemmS<0><<<dim3(1, 3*CD/128), blk, 0, stream>>>(updb, wihTh, wihTm, CBS, 3*CD, CD, CD,
                nullptr, 0, giRaw);
            hgemmS<0><<<dim3(1, 3*CD/128), blk, 0, stream>>>(slots, whhTh, whhTm, CBS, 3*CD, CD, CD,
                nullptr, 0, ghRaw);
            gate_ln_kernel<<<CBS, blk, 0, stream>>>(giRaw, ghRaw, gru_bih, gru_bhh, slots,
                mlp_ln_g, mlp_ln_b, snewb, sMb);
            // h1 = relu(sM @ w1 + b1)
            hgemmS<0><<<dim3(1, 4*CD/128), blk, 0, stream>>>(sMb, w1Th, w1Tm, CBS, 4*CD, CD, CD,
                mlp_b1, 1, h1b);
            // Macc = h1 @ w2  (K=1024, 4-way K-split, atomic)
            hipMemsetAsync(Macc, 0, (size_t)CBS * CD * sizeof(float), stream);
            hgemmS<1><<<dim3(1, CD/128, 4), blk, 0, stream>>>(h1b, w2Th, w2Tm, CBS, CD, 4*CD, CD,
                nullptr, 0, Macc);
            residual_kernel<<<CBS, blk, 0, stream>>>(snewb, mlp_b2, Macc, slots);
        }
    }
    // out0 = slots @ fin_w + fin_b
    hgemmS<0><<<dim3(1, CD/128), blk, 0, stream>>>(slots, finTh, finTm, CBS, CD, CD, CD,
        fin_b, 0, out0);
}

// Round 10
// 817.715 us; speedup vs baseline: 1.3203x; 1.3203x over previous
//
#include <hip/hip_runtime.h>

// ---------------- problem constants ----------------
constexpr int CB   = 8;      // batch
constexpr int CN   = 1369;   // tokens (37*37)
constexpr int CDIN = 768;
constexpr int CS   = 7;      // slots
constexpr int CD   = 256;
constexpr int CITERS = 3;
constexpr int CRES = 37;
constexpr float CSIGMA = 5.0f;
constexpr int CBS = CB * CS;        // 56
constexpr int CBN = CB * CN;        // 10952 rows for initial mlp
constexpr float LNEPS = 1e-5f;
constexpr float ATTN_EPS = 1e-8f;

typedef unsigned short u16;
typedef short bs8 __attribute__((ext_vector_type(8)));   // 8 bf16 (bit pattern in shorts)
typedef float f4 __attribute__((ext_vector_type(4)));

// ---------------- helpers ----------------
__device__ __forceinline__ float ag_x(int n) { return -1.f + (float)(n % CRES) * (2.f / 36.f); }
__device__ __forceinline__ float ag_y(int n) { return -1.f + (float)(n / CRES) * (2.f / 36.f); }

__device__ __forceinline__ u16 bf_rne(float f) {
    unsigned u = __float_as_uint(f);
    return (u16)((u + 0x7FFFu + ((u >> 16) & 1u)) >> 16);
}
__device__ __forceinline__ float bf_to_f(u16 h) { return __uint_as_float(((unsigned)h) << 16); }

__device__ __forceinline__ void split2b(float v, u16& h, u16& m) {
    h = bf_rne(v);
    m = bf_rne(v - bf_to_f(h));
}

// 256-thread block sum
__device__ __forceinline__ float block_reduce_sum(float v, float* sbuf) {
    #pragma unroll
    for (int off = 32; off > 0; off >>= 1) v += __shfl_down(v, off, 64);
    if ((threadIdx.x & 63) == 0) sbuf[threadIdx.x >> 6] = v;
    __syncthreads();
    if (threadIdx.x == 0) sbuf[0] = sbuf[0] + sbuf[1] + sbuf[2] + sbuf[3];
    __syncthreads();
    float r = sbuf[0];
    __syncthreads();
    return r;
}

// ---------------- layernorm (fp32 out) ----------------
__global__ __launch_bounds__(256) void ln_kernel(const float* __restrict__ in,
        float* __restrict__ out, const float* __restrict__ g,
        const float* __restrict__ b, int d) {
    __shared__ float sbuf[8];
    int row = blockIdx.x;
    const float* x = in + (size_t)row * d;
    float* y = out + (size_t)row * d;
    float s = 0.f;
    for (int i = threadIdx.x; i < d; i += 256) s += x[i];
    float mean = block_reduce_sum(s, sbuf) / d;
    float v = 0.f;
    for (int i = threadIdx.x; i < d; i += 256) { float t = x[i] - mean; v += t * t; }
    float var = block_reduce_sum(v, sbuf) / d;
    float rstd = rsqrtf(var + LNEPS);
    for (int i = threadIdx.x; i < d; i += 256) y[i] = (x[i] - mean) * rstd * g[i] + b[i];
}

// ---------------- transpose fp32 W[K][N] -> 2 bf16 planes Wt[N][K] ----------------
__global__ __launch_bounds__(256) void transpose_split2_kernel(const float* __restrict__ W,
        u16* __restrict__ Th, u16* __restrict__ Tm, int K, int N) {
    __shared__ float tile[32][33];
    int nb = blockIdx.x * 32, kb = blockIdx.y * 32;
    int tx = threadIdx.x & 31, ty = threadIdx.x >> 5;   // ty 0..7
    #pragma unroll
    for (int i = 0; i < 32; i += 8)
        tile[ty + i][tx] = W[(size_t)(kb + ty + i) * N + nb + tx];
    __syncthreads();
    #pragma unroll
    for (int i = 0; i < 32; i += 8) {
        float v = tile[tx][ty + i];
        u16 h, m; split2b(v, h, m);
        size_t idx = (size_t)(nb + ty + i) * K + kb + tx;
        Th[idx] = h; Tm[idx] = m;
    }
}

// ---------------- fp32 transpose W[K][N] -> T[N][K] ----------------
__global__ __launch_bounds__(256) void transpose32_kernel(const float* __restrict__ W,
        float* __restrict__ T, int K, int N) {
    __shared__ float tile[32][33];
    int nb = blockIdx.x * 32, kb = blockIdx.y * 32;
    int tx = threadIdx.x & 31, ty = threadIdx.x >> 5;
    #pragma unroll
    for (int i = 0; i < 32; i += 8)
        tile[ty + i][tx] = W[(size_t)(kb + ty + i) * N + nb + tx];
    __syncthreads();
    #pragma unroll
    for (int i = 0; i < 32; i += 8)
        T[(size_t)(nb + ty + i) * K + kb + tx] = tile[tx][ty + i];
}

// ---------------- P[k][n] = sum_j A[k][j]*B[j][n], A [256][256], B [256][N] ----------------
__global__ __launch_bounds__(256) void wprodN_kernel(const float* __restrict__ A,
        const float* __restrict__ B, float* __restrict__ P, int N) {
    __shared__ float arow[CD];
    int k = blockIdx.x;
    arow[threadIdx.x] = A[k * CD + threadIdx.x];
    __syncthreads();
    int n = blockIdx.y * 256 + threadIdx.x;
    if (n >= N) return;
    float acc = 0.f;
    for (int j = 0; j < CD; j++) acc += arow[j] * B[(size_t)j * N + n];
    P[(size_t)k * N + n] = acc;
}

// G2[g][n] = sum_j g_w[g][j]*f_w1[j][n];  gb1[n] = sum_j g_b[j]*f_w1[j][n] + f_b1[n]
__global__ __launch_bounds__(256) void g2_kernel(const float* __restrict__ g_w,
        const float* __restrict__ g_b, const float* __restrict__ f_w1,
        const float* __restrict__ f_b1, float* __restrict__ G2, float* __restrict__ gb1) {
    int n = threadIdx.x;
    float a0 = 0.f, a1 = 0.f, ab = 0.f;
    for (int j = 0; j < CD; j++) {
        float w = f_w1[j * CD + n];
        a0 += g_w[j] * w;
        a1 += g_w[CD + j] * w;
        ab += g_b[j] * w;
    }
    G2[n] = a0; G2[CD + n] = a1; gb1[n] = ab + f_b1[n];
}

// bg[n] = sum_c f_b2[c]*wih[c][n] + bih[n]   (N=768)
__global__ __launch_bounds__(256) void bg_kernel(const float* __restrict__ f_b2,
        const float* __restrict__ wih, const float* __restrict__ bih,
        float* __restrict__ bg, int N) {
    int n = blockIdx.x * 256 + threadIdx.x;
    if (n >= N) return;
    float s = bih[n];
    for (int c = 0; c < CD; c++) s += f_b2[c] * wih[(size_t)c * N + n];
    bg[n] = s;
}

// wqb[j] = sum_c Wq[j][c] * f_b2[c]
__global__ __launch_bounds__(256) void wqb_kernel(const float* __restrict__ Wq,
        const float* __restrict__ f_b2, float* __restrict__ wqb) {
    int j = threadIdx.x;
    float s = 0.f;
    for (int c = 0; c < CD; c++) s += Wq[j * CD + c] * f_b2[c];
    wqb[j] = s;
}

// ---------------- bf16x3 (split-2 planes) TN GEMM — big M (init phase) ----------------
// grid = (N/128, M/128): x-fastest dispatch => consecutive blocks share the A-tile (L2 reuse)
__global__ __launch_bounds__(256)
void hgemm(const float* __restrict__ A,
           const u16* __restrict__ Bh, const u16* __restrict__ Bm,
           int M, int N, int K, const float* __restrict__ bias, int relu,
           float* __restrict__ Cf) {
    constexpr int PK = 40;
    __shared__ short smem[4 * 128 * PK];         // 40 KB
    short* Ash = smem;
    short* Asm_ = smem + 128 * PK;
    short* Bsh = smem + 2 * 128 * PK;
    short* Bsm = smem + 3 * 128 * PK;
    const int tid = threadIdx.x;
    const int m0 = blockIdx.y * 128, n0 = blockIdx.x * 128;
    const int w = tid >> 6, lane = tid & 63;
    const int wm = w & 1, wn = w >> 1;
    const int l15 = lane & 15, l4 = lane >> 4;
    const int sr = tid >> 2;
    const int sc = (tid & 3) * 8;

    const float* asrc[2];
    #pragma unroll
    for (int it = 0; it < 2; it++) {
        int grow = m0 + sr + it * 64;
        int gcl = grow < M ? grow : M - 1;
        asrc[it] = A + (size_t)gcl * K + sc;
    }

    f4 acc[4][4];
    #pragma unroll
    for (int i = 0; i < 4; i++)
        #pragma unroll
        for (int j = 0; j < 4; j++) acc[i][j] = (f4){0.f, 0.f, 0.f, 0.f};

    for (int k0 = 0; k0 < K; k0 += 32) {
        #pragma unroll
        for (int it = 0; it < 2; it++) {
            int r = sr + it * 64;
            float v8[8];
            const float* p = asrc[it] + k0;
            *(float4*)&v8[0] = *(const float4*)(p);
            *(float4*)&v8[4] = *(const float4*)(p + 4);
            bs8 hv, mv;
            #pragma unroll
            for (int j = 0; j < 8; j++) {
                u16 h, m; split2b(v8[j], h, m);
                hv[j] = (short)h; mv[j] = (short)m;
            }
            *(bs8*)(Ash  + r * PK + sc) = hv;
            *(bs8*)(Asm_ + r * PK + sc) = mv;
            int nr = n0 + r;
            size_t bofs = (size_t)nr * K + k0 + sc;
            *(bs8*)(Bsh + r * PK + sc) = *(const bs8*)(Bh + bofs);
            *(bs8*)(Bsm + r * PK + sc) = *(const bs8*)(Bm + bofs);
        }
        __syncthreads();
        bs8 ah[4], am[4], bh[4], bm[4];
        #pragma unroll
        for (int f = 0; f < 4; f++) {
            int ra = (wm * 64 + f * 16 + l15) * PK + l4 * 8;
            ah[f] = *(const bs8*)(Ash  + ra);
            am[f] = *(const bs8*)(Asm_ + ra);
            int rb = (wn * 64 + f * 16 + l15) * PK + l4 * 8;
            bh[f] = *(const bs8*)(Bsh + rb);
            bm[f] = *(const bs8*)(Bsm + rb);
        }
        #pragma unroll
        for (int mf = 0; mf < 4; mf++)
            #pragma unroll
            for (int nf = 0; nf < 4; nf++) {
                acc[mf][nf] = __builtin_amdgcn_mfma_f32_16x16x32_bf16(am[mf], bh[nf], acc[mf][nf], 0, 0, 0);
                acc[mf][nf] = __builtin_amdgcn_mfma_f32_16x16x32_bf16(ah[mf], bm[nf], acc[mf][nf], 0, 0, 0);
                acc[mf][nf] = __builtin_amdgcn_mfma_f32_16x16x32_bf16(ah[mf], bh[nf], acc[mf][nf], 0, 0, 0);
            }
        __syncthreads();
    }

    #pragma unroll
    for (int mf = 0; mf < 4; mf++)
        #pragma unroll
        for (int i = 0; i < 4; i++) {
            int grow = m0 + wm * 64 + mf * 16 + l4 * 4 + i;
            if (grow < M) {
                #pragma unroll
                for (int nf = 0; nf < 4; nf++) {
                    int col = n0 + wn * 64 + nf * 16 + l15;
                    float v = acc[mf][nf][i] + (bias ? bias[col] : 0.f);
                    if (relu) v = fmaxf(v, 0.f);
                    Cf[(size_t)grow * N + col] = v;
                }
            }
        }
}

// ---------------- thin fp32 row-GEMV: C[r][c] = act(sum_k A[r][k]*W[k][c] + bias[c]) (+resid) ----------------
// grid (M, N/128), 128 threads. W in ORIGINAL [K][N] layout (coalesced). A row staged in LDS.
__global__ __launch_bounds__(128) void rowgemm_kernel(const float* __restrict__ A,
        const float* __restrict__ W, const float* __restrict__ bias,
        float* __restrict__ C, int N, int K, int relu,
        const float* __restrict__ resid, const float* __restrict__ resb) {
    __shared__ float sA[1024];
    int r = blockIdx.x;
    int c = blockIdx.y * 128 + threadIdx.x;
    for (int i = threadIdx.x; i < K; i += 128) sA[i] = A[(size_t)r * K + i];
    __syncthreads();
    float a0 = 0.f, a1 = 0.f, a2 = 0.f, a3 = 0.f;
    #pragma unroll 4
    for (int k = 0; k < K; k += 4) {
        a0 += sA[k]     * W[(size_t)k * N + c];
        a1 += sA[k + 1] * W[(size_t)(k + 1) * N + c];
        a2 += sA[k + 2] * W[(size_t)(k + 2) * N + c];
        a3 += sA[k + 3] * W[(size_t)(k + 3) * N + c];
    }
    float v = (a0 + a1) + (a2 + a3) + (bias ? bias[c] : 0.f);
    if (relu) v = fmaxf(v, 0.f);
    if (resid) v += resid[(size_t)r * N + c] + resb[c];
    C[(size_t)r * N + c] = v;
}

// gi/gh pair in one launch via blockIdx.z
__global__ __launch_bounds__(128) void rowgemmG_kernel(
        const float* __restrict__ A0, const float* __restrict__ W0,
        const float* __restrict__ b0, float* __restrict__ C0,
        const float* __restrict__ A1, const float* __restrict__ W1,
        const float* __restrict__ b1, float* __restrict__ C1,
        int N, int K) {
    __shared__ float sA[256];
    const float* A = blockIdx.z ? A1 : A0;
    const float* W = blockIdx.z ? W1 : W0;
    const float* B = blockIdx.z ? b1 : b0;
    float* C = blockIdx.z ? C1 : C0;
    int r = blockIdx.x;
    int c = blockIdx.y * 128 + threadIdx.x;
    for (int i = threadIdx.x; i < K; i += 128) sA[i] = A[(size_t)r * K + i];
    __syncthreads();
    float a0 = 0.f, a1 = 0.f, a2 = 0.f, a3 = 0.f;
    #pragma unroll 4
    for (int k = 0; k < K; k += 4) {
        a0 += sA[k]     * W[(size_t)k * N + c];
        a1 += sA[k + 1] * W[(size_t)(k + 1) * N + c];
        a2 += sA[k + 2] * W[(size_t)(k + 2) * N + c];
        a3 += sA[k + 3] * W[(size_t)(k + 3) * N + c];
    }
    C[(size_t)r * N + c] = (a0 + a1) + (a2 + a3) + B[c];
}

// ---------------- small kernels ----------------
__global__ __launch_bounds__(256) void init_kernel(const float* __restrict__ slots_init_p,
        const float* __restrict__ S_s0, const float* __restrict__ S_p0,
        float* __restrict__ slots, float* __restrict__ S_s, float* __restrict__ S_p) {
    int bs = blockIdx.x, t = threadIdx.x;
    int s = bs % CS;
    slots[bs * CD + t] = slots_init_p[s * CD + t];
    if (t < 2) { S_s[bs * 2 + t] = S_s0[s * 2 + t]; S_p[bs * 2 + t] = S_p0[s * 2 + t]; }
}

// LN(slots) -> snb; qb0[bs] = sn . wqb
__global__ __launch_bounds__(256) void ln_slots_kernel(const float* __restrict__ slots,
        const float* __restrict__ ln_g, const float* __restrict__ ln_b,
        const float* __restrict__ wqb, float* __restrict__ snb, float* __restrict__ qb0) {
    __shared__ float sbuf[8];
    int row = blockIdx.x, t = threadIdx.x;
    float x = slots[row * CD + t];
    float mean = block_reduce_sum(x, sbuf) / CD;
    float d0 = x - mean;
    float var = block_reduce_sum(d0 * d0, sbuf) / CD;
    float sn = d0 * rsqrtf(var + LNEPS) * ln_g[t] + ln_b[t];
    snb[row * CD + t] = sn;
    float qb = block_reduce_sum(sn * wqb[t], sbuf);
    if (t == 0) qb0[row] = qb;
}

// dots[(b,s),n] = scale*( qw[bs] . relu(KXW1[b,n] + r0*G2[0] + r1*G2[1] + gb1) + qb0[bs] )
__global__ __launch_bounds__(256) void dots_kernel(const float* __restrict__ KXW1,
        const float* __restrict__ S_p, const float* __restrict__ S_s,
        const float* __restrict__ G2, const float* __restrict__ gb1,
        const float* __restrict__ qw, const float* __restrict__ qb0,
        float* __restrict__ dots) {
    int b = blockIdx.x;
    int w = threadIdx.x >> 6, l = threadIdx.x & 63;
    int k4 = l * 4;
    float4 g0 = *(const float4*)(G2 + k4);
    float4 g1 = *(const float4*)(G2 + CD + k4);
    float4 gb = *(const float4*)(gb1 + k4);
    float4 qwv[CS]; float px[CS], py[CS], ix[CS], iy[CS], q0[CS];
    #pragma unroll
    for (int s = 0; s < CS; s++) {
        int bs = b * CS + s;
        qwv[s] = *(const float4*)(qw + bs * CD + k4);
        px[s] = S_p[2 * bs]; py[s] = S_p[2 * bs + 1];
        ix[s] = 1.f / (S_s[2 * bs] * CSIGMA); iy[s] = 1.f / (S_s[2 * bs + 1] * CSIGMA);
        q0[s] = qb0[bs];
    }
    int nbase = blockIdx.y * 32 + w * 8;
    #pragma unroll 2
    for (int i = 0; i < 8; i++) {
        int n = nbase + i;
        int nc = n < CN ? n : CN - 1;
        float4 kx = *(const float4*)(KXW1 + (size_t)(b * CN + nc) * CD + k4);
        float ax = ag_x(nc), ay = ag_y(nc);
        #pragma unroll
        for (int s = 0; s < CS; s++) {
            float r0 = (ax - px[s]) * ix[s];
            float r1 = (ay - py[s]) * iy[s];
            float v0 = fmaxf(kx.x + r0 * g0.x + r1 * g1.x + gb.x, 0.f);
            float v1 = fmaxf(kx.y + r0 * g0.y + r1 * g1.y + gb.y, 0.f);
            float v2 = fmaxf(kx.z + r0 * g0.z + r1 * g1.z + gb.z, 0.f);
            float v3 = fmaxf(kx.w + r0 * g0.w + r1 * g1.w + gb.w, 0.f);
            float d = v0 * qwv[s].x + v1 * qwv[s].y + v2 * qwv[s].z + v3 * qwv[s].w;
            #pragma unroll
            for (int off = 32; off > 0; off >>= 1) d += __shfl_down(d, off, 64);
            if (l == 0 && n < CN) dots[(size_t)(b * CS + s) * CN + n] = 0.0625f * (d + q0[s]);
        }
    }
}

// Wacc[bs][k] += sum_n attn[bs,n] * relu(VXW1[b,n,k] + r0*G2[0][k] + r1*G2[1][k] + gb1[k])
__global__ __launch_bounds__(256) void vsum_kernel(const float* __restrict__ VXW1,
        const float* __restrict__ S_p, const float* __restrict__ S_s,
        const float* __restrict__ G2, const float* __restrict__ gb1,
        const float* __restrict__ attn, float* __restrict__ Wacc) {
    __shared__ float sred[4 * CD];
    int b = blockIdx.x;
    int w = threadIdx.x >> 6, l = threadIdx.x & 63;
    int k4 = l * 4;
    float4 g0 = *(const float4*)(G2 + k4);
    float4 g1 = *(const float4*)(G2 + CD + k4);
    float4 gb = *(const float4*)(gb1 + k4);
    float px[CS], py[CS], ix[CS], iy[CS];
    #pragma unroll
    for (int s = 0; s < CS; s++) {
        int bs = b * CS + s;
        px[s] = S_p[2 * bs]; py[s] = S_p[2 * bs + 1];
        ix[s] = 1.f / (S_s[2 * bs] * CSIGMA); iy[s] = 1.f / (S_s[2 * bs + 1] * CSIGMA);
    }
    float4 acc[CS];
    #pragma unroll
    for (int s = 0; s < CS; s++) acc[s] = make_float4(0.f, 0.f, 0.f, 0.f);
    int nbase = blockIdx.y * 32 + w * 8;
    #pragma unroll 2
    for (int i = 0; i < 8; i++) {
        int n = nbase + i;
        int nc = n < CN ? n : CN - 1;
        float4 vx = *(const float4*)(VXW1 + (size_t)(b * CN + nc) * CD + k4);
        float ax = ag_x(nc), ay = ag_y(nc);
        #pragma unroll
        for (int s = 0; s < CS; s++) {
            float r0 = (ax - px[s]) * ix[s];
            float r1 = (ay - py[s]) * iy[s];
            float a = (n < CN) ? attn[(size_t)(b * CS + s) * CN + n] : 0.f;
            acc[s].x += a * fmaxf(vx.x + r0 * g0.x + r1 * g1.x + gb.x, 0.f);
            acc[s].y += a * fmaxf(vx.y + r0 * g0.y + r1 * g1.y + gb.y, 0.f);
            acc[s].z += a * fmaxf(vx.z + r0 * g0.z + r1 * g1.z + gb.z, 0.f);
            acc[s].w += a * fmaxf(vx.w + r0 * g0.w + r1 * g1.w + gb.w, 0.f);
        }
    }
    for (int s = 0; s < CS; s++) {
        ((float4*)sred)[w * 64 + l] = acc[s];
        __syncthreads();
        if (threadIdx.x < CD) {
            float v = sred[threadIdx.x] + sred[CD + threadIdx.x]
                    + sred[2 * CD + threadIdx.x] + sred[3 * CD + threadIdx.x];
            atomicAdd(&Wacc[(size_t)(b * CS + s) * CD + threadIdx.x], v);
        }
        __syncthreads();
    }
}

__global__ __launch_bounds__(256) void softmax_kernel(float* __restrict__ dots) {
    int idx = blockIdx.x * 256 + threadIdx.x;
    if (idx >= CBN) return;
    int b = idx / CN, n = idx - b * CN;
    float v[CS]; float mx = -1e30f;
    #pragma unroll
    for (int s = 0; s < CS; s++) { v[s] = dots[(size_t)(b * CS + s) * CN + n]; mx = fmaxf(mx, v[s]); }
    float sum = 0.f;
    #pragma unroll
    for (int s = 0; s < CS; s++) { v[s] = __expf(v[s] - mx); sum += v[s]; }
    float inv = 1.f / sum;
    #pragma unroll
    for (int s = 0; s < CS; s++) dots[(size_t)(b * CS + s) * CN + n] = v[s] * inv + ATTN_EPS;
}

__global__ __launch_bounds__(256) void attn_moments_kernel(float* __restrict__ u,
        float* __restrict__ S_p, float* __restrict__ S_s) {
    __shared__ float sbuf[8];
    int bs = blockIdx.x;
    float* up = u + (size_t)bs * CN;
    float m0 = 0, m1x = 0, m1y = 0, m2x = 0, m2y = 0;
    for (int n = threadIdx.x; n < CN; n += 256) {
        float uu = up[n];
        float ax = ag_x(n), ay = ag_y(n);
        m0 += uu; m1x += uu * ax; m1y += uu * ay; m2x += uu * ax * ax; m2y += uu * ay * ay;
    }
    m0  = block_reduce_sum(m0, sbuf);
    m1x = block_reduce_sum(m1x, sbuf);
    m1y = block_reduce_sum(m1y, sbuf);
    m2x = block_reduce_sum(m2x, sbuf);
    m2y = block_reduce_sum(m2y, sbuf);
    float px = m1x / m0, py = m1y / m0;
    if (threadIdx.x == 0) {
        S_p[2 * bs] = px; S_p[2 * bs + 1] = py;
        S_s[2 * bs]     = sqrtf(fmaxf(m2x / m0 - px * px, 0.f));
        S_s[2 * bs + 1] = sqrtf(fmaxf(m2y / m0 - py * py, 0.f));
    }
    float inv = 1.f / m0;
    for (int n = threadIdx.x; n < CN; n += 256) up[n] = up[n] * inv;
}

// gates + LN (biases already folded into giRaw/ghRaw)
__global__ __launch_bounds__(256) void gate_ln_kernel(const float* __restrict__ giRaw,
        const float* __restrict__ ghRaw, const float* __restrict__ slots,
        const float* __restrict__ mg, const float* __restrict__ mb,
        float* __restrict__ snewb, float* __restrict__ sMb) {
    __shared__ float sbuf[8];
    int row = blockIdx.x, t = threadIdx.x;
    float gi0 = giRaw[row * 3 * CD + t];
    float gi1 = giRaw[row * 3 * CD + CD + t];
    float gi2 = giRaw[row * 3 * CD + 2 * CD + t];
    float gh0 = ghRaw[row * 3 * CD + t];
    float gh1 = ghRaw[row * 3 * CD + CD + t];
    float gh2 = ghRaw[row * 3 * CD + 2 * CD + t];
    float r = 1.f / (1.f + expf(-(gi0 + gh0)));
    float z = 1.f / (1.f + expf(-(gi1 + gh1)));
    float nn = tanhf(gi2 + r * gh2);
    float snew = (1.f - z) * nn + z * slots[row * CD + t];
    snewb[row * CD + t] = snew;
    float mean = block_reduce_sum(snew, sbuf) / CD;
    float dv = snew - mean;
    float var = block_reduce_sum(dv * dv, sbuf) / CD;
    sMb[row * CD + t] = dv * rsqrtf(var + LNEPS) * mg[t] + mb[t];
}

// ---------------- launcher ----------------
extern "C" void kernel_launch(void* const* d_in, const int* in_sizes, int n_in,
                              void* d_out, int out_size, void* d_ws, size_t ws_size,
                              hipStream_t stream) {
    (void)in_sizes; (void)n_in; (void)out_size;
    const float* inputs       = (const float*)d_in[0];
    const float* slots_init_p = (const float*)d_in[1];
    const float* S_s0         = (const float*)d_in[2];
    const float* S_p0         = (const float*)d_in[3];
    const float* im_ln1_g = (const float*)d_in[4];
    const float* im_ln1_b = (const float*)d_in[5];
    const float* im_w1    = (const float*)d_in[6];
    const float* im_b1    = (const float*)d_in[7];
    const float* im_w2    = (const float*)d_in[8];
    const float* im_b2    = (const float*)d_in[9];
    const float* im_ln2_g = (const float*)d_in[10];
    const float* im_ln2_b = (const float*)d_in[11];
    const float* Wq  = (const float*)d_in[12];
    const float* Wk  = (const float*)d_in[13];
    const float* Wv  = (const float*)d_in[14];
    const float* g_w = (const float*)d_in[15];
    const float* g_b = (const float*)d_in[16];
    const float* f_w1 = (const float*)d_in[17];
    const float* f_b1 = (const float*)d_in[18];
    const float* f_w2 = (const float*)d_in[19];
    const float* f_b2 = (const float*)d_in[20];
    const float* ln_g = (const float*)d_in[21];
    const float* ln_b = (const float*)d_in[22];
    const float* gru_wih = (const float*)d_in[23];
    const float* gru_whh = (const float*)d_in[24];
    const float* gru_bih = (const float*)d_in[25];
    const float* gru_bhh = (const float*)d_in[26];
    const float* mlp_ln_g = (const float*)d_in[27];
    const float* mlp_ln_b = (const float*)d_in[28];
    const float* mlp_w1 = (const float*)d_in[29];
    const float* mlp_b1 = (const float*)d_in[30];
    const float* mlp_w2 = (const float*)d_in[31];
    const float* mlp_b2 = (const float*)d_in[32];
    const float* fin_w = (const float*)d_in[33];
    const float* fin_b = (const float*)d_in[34];

    char* base = (char*)d_ws;
    size_t off = 0;
    auto take = [&](size_t bytes) { void* p = base + off; off += (bytes + 255) & ~(size_t)255; return p; };

    float* R1 = (float*)take((size_t)CBN * CDIN * 4);  // xln; later xD | xDn
    float* R2 = (float*)take((size_t)CBN * CDIN * 4);  // X1; later KXW1 | VXW1
    u16* w1th = (u16*)take((size_t)CDIN * CDIN * 2);
    u16* w1tm = (u16*)take((size_t)CDIN * CDIN * 2);
    u16* w2th = (u16*)take((size_t)CDIN * CD * 2);
    u16* w2tm = (u16*)take((size_t)CDIN * CD * 2);
    float* Pk   = (float*)take((size_t)CD * CD * 4);
    float* Pv   = (float*)take((size_t)CD * CD * 4);
    u16* pkth = (u16*)take((size_t)CD * CD * 2);
    u16* pktm = (u16*)take((size_t)CD * CD * 2);
    u16* pvth = (u16*)take((size_t)CD * CD * 2);
    u16* pvtm = (u16*)take((size_t)CD * CD * 2);
    float* G2b  = (float*)take((size_t)2 * CD * 4);
    float* gb1b = (float*)take((size_t)CD * 4);
    float* fw2T = (float*)take((size_t)CD * CD * 4);   // f_w2^T fp32
    float* Pq   = (float*)take((size_t)CD * CD * 4);   // [K][N]: sum_c Wq[k][c] f_w2[n][c]
    float* Pg   = (float*)take((size_t)CD * 3 * CD * 4); // f_w2 @ wih  [256][768]
    float* bgv  = (float*)take((size_t)3 * CD * 4);
    float* wqbb = (float*)take((size_t)CD * 4);
    float* snb   = (float*)take((size_t)CBS * CD * 4);
    float* qwb   = (float*)take((size_t)CBS * CD * 4);
    float* qb0b  = (float*)take((size_t)CBS * 4);
    float* Wacc  = (float*)take((size_t)CBS * CD * 4);
    float* giRaw = (float*)take((size_t)CBS * 3 * CD * 4);
    float* ghRaw = (float*)take((size_t)CBS * 3 * CD * 4);
    float* snewb = (float*)take((size_t)CBS * CD * 4);
    float* sMb   = (float*)take((size_t)CBS * CD * 4);
    float* h1b   = (float*)take((size_t)CBS * 4 * CD * 4);
    float* S_pA  = (float*)take((size_t)CBS * 2 * 4);
    float* S_sA  = (float*)take((size_t)CBS * 2 * 4);
    float* S_pB  = (float*)take((size_t)CBS * 2 * 4);
    float* S_sB  = (float*)take((size_t)CBS * 2 * 4);
    float* slots = (float*)take((size_t)CBS * CD * 4);
    if (ws_size < off) return;

    float* xln  = R1;
    float* xD   = R1;
    float* xDn  = R1 + (size_t)CBN * CD;
    float* X1   = R2;
    float* KXW1 = R2;
    float* VXW1 = R2 + (size_t)CBN * CD;

    float* out0 = (float*)d_out;            // [CBS,CD]
    float* attnb = out0 + CBS * CD;         // [CBS,CN] — dots/attn buffer

    dim3 blk(256);
    const int gM_bn = (CBN + 127) / 128;    // 86
    dim3 gridBN(CB, (CN + 31) / 32);        // 8 x 43

    // ---- weight prep ----
    transpose_split2_kernel<<<dim3(CDIN/32, CDIN/32), blk, 0, stream>>>(im_w1, w1th, w1tm, CDIN, CDIN);
    transpose_split2_kernel<<<dim3(CD/32,   CDIN/32), blk, 0, stream>>>(im_w2, w2th, w2tm, CDIN, CD);
    wprodN_kernel<<<dim3(CD, 1), blk, 0, stream>>>(Wk, f_w1, Pk, CD);
    wprodN_kernel<<<dim3(CD, 1), blk, 0, stream>>>(Wv, f_w1, Pv, CD);
    transpose_split2_kernel<<<dim3(CD/32, CD/32), blk, 0, stream>>>(Pk, pkth, pktm, CD, CD);
    transpose_split2_kernel<<<dim3(CD/32, CD/32), blk, 0, stream>>>(Pv, pvth, pvtm, CD, CD);
    g2_kernel<<<1, blk, 0, stream>>>(g_w, g_b, f_w1, f_b1, G2b, gb1b);
    transpose32_kernel<<<dim3(CD/32, CD/32), blk, 0, stream>>>(f_w2, fw2T, CD, CD);
    wprodN_kernel<<<dim3(CD, 1), blk, 0, stream>>>(Wq, fw2T, Pq, CD);
    wprodN_kernel<<<dim3(CD, 3), blk, 0, stream>>>(f_w2, gru_wih, Pg, 3 * CD);
    bg_kernel<<<3, blk, 0, stream>>>(f_b2, gru_wih, gru_bih, bgv, 3 * CD);
    wqb_kernel<<<1, blk, 0, stream>>>(Wq, f_b2, wqbb);

    // ---- initial mlp (grid: x = N-tiles for L2 A-tile sharing) ----
    ln_kernel<<<CBN, blk, 0, stream>>>(inputs, xln, im_ln1_g, im_ln1_b, CDIN);
    hgemm<<<dim3(CDIN/128, gM_bn), blk, 0, stream>>>(xln, w1th, w1tm, CBN, CDIN, CDIN, im_b1, 1, X1);
    hgemm<<<dim3(CD/128, gM_bn), blk, 0, stream>>>(X1, w2th, w2tm, CBN, CD, CDIN, im_b2, 0, xD);
    ln_kernel<<<CBN, blk, 0, stream>>>(xD, xDn, im_ln2_g, im_ln2_b, CD);
    hgemm<<<dim3(CD/128, gM_bn), blk, 0, stream>>>(xDn, pkth, pktm, CBN, CD, CD, nullptr, 0, KXW1);
    hgemm<<<dim3(CD/128, gM_bn), blk, 0, stream>>>(xDn, pvth, pvtm, CBN, CD, CD, nullptr, 0, VXW1);
    init_kernel<<<CBS, blk, 0, stream>>>(slots_init_p, S_s0, S_p0, slots, S_sA, S_pA);

    for (int t = 0; t <= CITERS; t++) {
        float* Sp_cur = (t & 1) ? S_pB : S_pA;
        float* Ss_cur = (t & 1) ? S_sB : S_sA;
        float* Sp_nxt = (t & 1) ? S_pA : S_pB;
        float* Ss_nxt = (t & 1) ? S_sA : S_sB;
        ln_slots_kernel<<<CBS, blk, 0, stream>>>(slots, ln_g, ln_b, wqbb, snb, qb0b);
        // qw = sn @ Pq
        rowgemm_kernel<<<dim3(CBS, CD/128), dim3(128), 0, stream>>>(snb, Pq, nullptr, qwb,
            CD, CD, 0, nullptr, nullptr);
        dots_kernel<<<gridBN, blk, 0, stream>>>(KXW1, Sp_cur, Ss_cur, G2b, gb1b, qwb, qb0b, attnb);
        softmax_kernel<<<(CBN + 255) / 256, blk, 0, stream>>>(attnb);
        attn_moments_kernel<<<CBS, blk, 0, stream>>>(attnb, Sp_nxt, Ss_nxt);
        if (t < CITERS) {
            hipMemsetAsync(Wacc, 0, (size_t)CBS * CD * sizeof(float), stream);
            vsum_kernel<<<gridBN, blk, 0, stream>>>(VXW1, Sp_cur, Ss_cur, G2b, gb1b, attnb, Wacc);
            // giRaw = Wacc@Pg + bg ; ghRaw = slots@whh + bhh (one launch, z=2)
            rowgemmG_kernel<<<dim3(CBS, 3*CD/128, 2), dim3(128), 0, stream>>>(
                Wacc, Pg, bgv, giRaw, slots, gru_whh, gru_bhh, ghRaw, 3 * CD, CD);
            gate_ln_kernel<<<CBS, blk, 0, stream>>>(giRaw, ghRaw, slots,
                mlp_ln_g, mlp_ln_b, snewb, sMb);
            // h1 = relu(sM @ w1 + b1)
            rowgemm_kernel<<<dim3(CBS, 4*CD/128), dim3(128), 0, stream>>>(sMb, mlp_w1, mlp_b1,
                h1b, 4 * CD, CD, 1, nullptr, nullptr);
            // slots = snew + b2 + h1 @ w2   (residual fused)
            rowgemm_kernel<<<dim3(CBS, CD/128), dim3(128), 0, stream>>>(h1b, mlp_w2, nullptr,
                slots, CD, 4 * CD, 0, snewb, mlp_b2);
        }
    }
    // out0 = slots @ fin_w + fin_b
    rowgemm_kernel<<<dim3(CBS, CD/128), dim3(128), 0, stream>>>(slots, fin_w, fin_b,
        out0, CD, CD, 0, nullptr, nullptr);
}